// Round 4
// baseline (508.289 us; speedup 1.0000x reference)
//
#include <hip/hip_runtime.h>
#include <stdint.h>

typedef unsigned short u16;
typedef __bf16 bf16_t;
typedef bf16_t bf16x8 __attribute__((ext_vector_type(8)));
typedef float f32x4 __attribute__((ext_vector_type(4)));

// f32 -> bf16 with round-to-nearest-even
__device__ __forceinline__ u16 f2b(float f) {
    union { float f; uint32_t i; } v; v.f = f;
    uint32_t r = v.i + 0x7FFFu + ((v.i >> 16) & 1u);
    return (u16)(r >> 16);
}
__device__ __forceinline__ uint4 pack8(float4 lo, float4 hi) {
    u16 tmp[8];
    tmp[0] = f2b(lo.x); tmp[1] = f2b(lo.y); tmp[2] = f2b(lo.z); tmp[3] = f2b(lo.w);
    tmp[4] = f2b(hi.x); tmp[5] = f2b(hi.y); tmp[6] = f2b(hi.z); tmp[7] = f2b(hi.w);
    return *(const uint4*)tmp;
}

// ---------------- GEMM core: C[M,N] = X[M,1024] @ W[1024,N] + bias ----------------
// WT = W^T in bf16 [N][K]. 128x128 tile, BK=32, 4 waves in 2x2 quadrants,
// 4x4 16x16x32 MFMA frags/wave. XF32: A operand is float32 in global (converted to
// bf16 during staging); else A is bf16 (u16). [R3: all external tensors are f32 —
// prior rounds' NaN = f32 misread as bf16.]
// mode 0: bf16 scatter-store to [B,H,S,D]; mode 1: float32 row-major [M,1024]
template<bool XF32>
__device__ __forceinline__ void gemm128(const void* __restrict__ Xv,
                                        const u16* __restrict__ WT,
                                        const float* __restrict__ bias,
                                        u16* __restrict__ dstb,
                                        float* __restrict__ dstf, int mode)
{
    __shared__ __align__(16) u16 As[128 * 32];
    __shared__ __align__(16) u16 Bs[128 * 32];
    const int t    = threadIdx.x;
    const int lane = t & 63;
    const int quad = lane >> 4;
    const int l15  = lane & 15;
    const int kc   = quad * 8;
    const int m0 = blockIdx.y * 128;
    const int n0 = blockIdx.x * 128;
    const int wave = t >> 6;
    const int wm = (wave >> 1) * 64;
    const int wn = (wave & 1) * 64;

    f32x4 acc[4][4];
#pragma unroll
    for (int i = 0; i < 4; i++)
#pragma unroll
        for (int j = 0; j < 4; j++)
#pragma unroll
            for (int r = 0; r < 4; r++) acc[i][j][r] = 0.0f;

    // staging map: thread t covers rows ar and ar+64, k-cols ac..ac+8 of each BK tile
    const int ar = t >> 2;
    const int ac = (t & 3) * 8;
    const float* xg32 = (const float*)Xv + (m0 + ar) * 1024 + ac;
    const u16*   xg16 = (const u16*)Xv   + (m0 + ar) * 1024 + ac;
    const u16*   wg   = WT + (n0 + ar) * 1024 + ac;

    for (int kt = 0; kt < 1024; kt += 32) {
        uint4 a0, a1;
        if (XF32) {
            const float4 a0l = *(const float4*)(xg32 + kt);
            const float4 a0h = *(const float4*)(xg32 + kt + 4);
            const float4 a1l = *(const float4*)(xg32 + 64 * 1024 + kt);
            const float4 a1h = *(const float4*)(xg32 + 64 * 1024 + kt + 4);
            a0 = pack8(a0l, a0h);
            a1 = pack8(a1l, a1h);
        } else {
            a0 = *(const uint4*)(xg16 + kt);
            a1 = *(const uint4*)(xg16 + 64 * 1024 + kt);
        }
        const uint4 b0 = *(const uint4*)(wg + kt);
        const uint4 b1 = *(const uint4*)(wg + 64 * 1024 + kt);
        __syncthreads();                    // prior tile's LDS reads complete
        *(uint4*)&As[t * 8]         = a0;
        *(uint4*)&As[(t + 256) * 8] = a1;
        *(uint4*)&Bs[t * 8]         = b0;
        *(uint4*)&Bs[(t + 256) * 8] = b1;
        __syncthreads();                    // staging visible
        bf16x8 af[4], bfv[4];
#pragma unroll
        for (int i = 0; i < 4; i++) {
            af[i]  = *(const bf16x8*)&As[(wm + i * 16 + l15) * 32 + kc];
            bfv[i] = *(const bf16x8*)&Bs[(wn + i * 16 + l15) * 32 + kc];
        }
#pragma unroll
        for (int i = 0; i < 4; i++)
#pragma unroll
            for (int j = 0; j < 4; j++)
                acc[i][j] = __builtin_amdgcn_mfma_f32_16x16x32_bf16(af[i], bfv[j], acc[i][j], 0, 0, 0);
    }

    // epilogue: C row = quad*4 + r, col = lane&15 (m89-verified layout)
#pragma unroll
    for (int i = 0; i < 4; i++) {
        const int rb = m0 + wm + i * 16 + quad * 4;
#pragma unroll
        for (int j = 0; j < 4; j++) {
            const int col = n0 + wn + j * 16 + l15;
            const float bias_v = bias[col];
#pragma unroll
            for (int r = 0; r < 4; r++) {
                const float v = acc[i][j][r] + bias_v;
                const int gm = rb + r;
                if (mode == 0) {
                    const int b = gm >> 11, s = gm & 2047;
                    const int h = col >> 6, d = col & 63;
                    dstb[((b * 16 + h) * 2048 + s) * 64 + d] = f2b(v);
                } else {
                    dstf[gm * 1024 + col] = v;
                }
            }
        }
    }
}

__global__ __launch_bounds__(256)
void qkv_kernel(const float* __restrict__ q_in, const float* __restrict__ k_in,
                const float* __restrict__ v_in, const u16* __restrict__ WT,
                const float* __restrict__ bq, const float* __restrict__ bk,
                const float* __restrict__ bv,
                u16* __restrict__ Qo, u16* __restrict__ Ko, u16* __restrict__ Vo)
{
    const int z = blockIdx.z;
    const float* X   = (z == 0) ? q_in : (z == 1) ? k_in : v_in;
    const u16* wt    = WT + ((z == 0) ? 2 : (z == 1) ? 1 : 0) * (1024 * 1024);
    const float* bias= (z == 0) ? bq : (z == 1) ? bk : bv;
    u16* dst         = (z == 0) ? Qo : (z == 1) ? Ko : Vo;
    gemm128<true>(X, wt, bias, dst, nullptr, 0);
}

__global__ __launch_bounds__(256)
void oproj_kernel(const u16* __restrict__ AO, const u16* __restrict__ WT,
                  const float* __restrict__ bo, float* __restrict__ out)
{
    gemm128<false>(AO, WT + 3 * 1024 * 1024, bo, nullptr, out, 1);
}

// ---------------- weight transpose+cvt: W[1024 k][1024 n] f32 -> WT[n][k] bf16 ----
__global__ void transpose_w(const float* __restrict__ Wv, const float* __restrict__ Wk,
                            const float* __restrict__ Wq, const float* __restrict__ Wo,
                            u16* __restrict__ WT)
{
    __shared__ u16 tile[64][65];
    const int z = blockIdx.z;
    const float* W = (z == 0) ? Wv : (z == 1) ? Wk : (z == 2) ? Wq : Wo;
    u16* dst = WT + z * 1024 * 1024;
    const int r0 = blockIdx.y * 64, c0 = blockIdx.x * 64;
    const int col = threadIdx.x & 63, rb = threadIdx.x >> 6;
#pragma unroll
    for (int r = rb; r < 64; r += 4) tile[r][col] = f2b(W[(r0 + r) * 1024 + c0 + col]);
    __syncthreads();
#pragma unroll
    for (int r = rb; r < 64; r += 4) dst[(c0 + r) * 1024 + r0 + col] = tile[col][r];
}

// ---------------- V transpose: V[bh][2048 s][64 d] -> VT[bh][64 d][2048 s] --------
__global__ void transpose_v(const u16* __restrict__ V, u16* __restrict__ VT)
{
    __shared__ u16 tile[64][65];
    const int bh = blockIdx.y, s0 = blockIdx.x * 64;
    const int col = threadIdx.x & 63, rb = threadIdx.x >> 6;
    const u16* src = V + bh * 2048 * 64;
    u16* dst = VT + bh * 64 * 2048;
#pragma unroll
    for (int r = rb; r < 64; r += 4) tile[r][col] = src[(s0 + r) * 64 + col];
    __syncthreads();
#pragma unroll
    for (int r = rb; r < 64; r += 4) dst[r * 2048 + s0 + col] = tile[col][r];
}

// ---------------- flash attention: Tq=64 per block, Tk=128 KV tiles ----------------
// grid (32 q-tiles, 64 bh). Wave w owns q-rows [w*16,+16). Online softmax per lane
// (rows quad*4+r). P round-trips through LDS with full barriers on both sides.
__global__ __launch_bounds__(256, 2)
void attn_kernel(const u16* __restrict__ Q, const u16* __restrict__ K,
                 const u16* __restrict__ VT, u16* __restrict__ AO)
{
    __shared__ __align__(16) u16 Qs[64 * 72];
    __shared__ __align__(16) u16 Ks[128 * 72];
    __shared__ __align__(16) u16 Ps[64 * 136];
    __shared__ __align__(16) u16 Vts[64 * 136];

    const int t    = threadIdx.x;
    const int lane = t & 63;
    const int wave = t >> 6;
    const int quad = lane >> 4;
    const int l15  = lane & 15;
    const int kc   = quad * 8;
    const int bh = blockIdx.y;
    const int qt = blockIdx.x;

    const u16* Qg = Q + (bh * 2048 + qt * 64) * 64;
    const u16* Kg = K + bh * 2048 * 64;
    const u16* Vg = VT + bh * 64 * 2048;

    // stage Q once; fold in 1/sqrt(64)=0.125 (exact in bf16)
#pragma unroll
    for (int c = 0; c < 2; c++) {
        const int chunk = t + c * 256;
        const int row = chunk >> 3;
        const int col = (chunk & 7) * 8;
        uint4 dv = *(const uint4*)&Qg[row * 64 + col];
        u16 tmp[8];
        *(uint4*)tmp = dv;
#pragma unroll
        for (int i = 0; i < 8; i++) {
            union { float f; uint32_t u; } x; x.u = ((uint32_t)tmp[i]) << 16;
            tmp[i] = f2b(x.f * 0.125f);
        }
        *(uint4*)&Qs[row * 72 + col] = *(const uint4*)tmp;
    }

    f32x4 o[4];
    float m_st[4], l_st[4];
#pragma unroll
    for (int dj = 0; dj < 4; dj++)
#pragma unroll
        for (int r = 0; r < 4; r++) o[dj][r] = 0.0f;
#pragma unroll
    for (int r = 0; r < 4; r++) { m_st[r] = -1.0e30f; l_st[r] = 0.0f; }

    for (int kv = 0; kv < 16; kv++) {
        const int j0 = kv * 128;
        __syncthreads();   // (a) previous tile's Ks/Vts reads complete (Qs vis on iter0)
#pragma unroll
        for (int c = 0; c < 4; c++) {
            const int chunk = t + c * 256;
            const int row = chunk >> 3;
            const int col = (chunk & 7) * 8;
            *(uint4*)&Ks[row * 72 + col] = *(const uint4*)&Kg[(j0 + row) * 64 + col];
        }
#pragma unroll
        for (int c = 0; c < 4; c++) {
            const int chunk = t + c * 256;
            const int row = chunk >> 4;
            const int col = (chunk & 15) * 8;
            *(uint4*)&Vts[row * 136 + col] = *(const uint4*)&Vg[row * 2048 + j0 + col];
        }
        __syncthreads();   // (b) staging visible

        // S = Q @ K^T : 8 col-frags x 2 k-steps
        f32x4 s[8];
#pragma unroll
        for (int n = 0; n < 8; n++)
#pragma unroll
            for (int r = 0; r < 4; r++) s[n][r] = 0.0f;
#pragma unroll
        for (int kk = 0; kk < 64; kk += 32) {
            const bf16x8 aq = *(const bf16x8*)&Qs[(wave * 16 + l15) * 72 + kk + kc];
#pragma unroll
            for (int n = 0; n < 8; n++) {
                const bf16x8 bk = *(const bf16x8*)&Ks[(n * 16 + l15) * 72 + kk + kc];
                s[n] = __builtin_amdgcn_mfma_f32_16x16x32_bf16(aq, bk, s[n], 0, 0, 0);
            }
        }

        // online softmax: row = wave*16 + quad*4 + r; reduce across quad's 16 lanes
        float rmax[4], rsum[4], alpha[4];
#pragma unroll
        for (int r = 0; r < 4; r++) {
            float m = s[0][r];
#pragma unroll
            for (int n = 1; n < 8; n++) m = fmaxf(m, s[n][r]);
            rmax[r] = m;
        }
#pragma unroll
        for (int d = 1; d < 16; d <<= 1)
#pragma unroll
            for (int r = 0; r < 4; r++)
                rmax[r] = fmaxf(rmax[r], __shfl_xor(rmax[r], d, 64));
#pragma unroll
        for (int r = 0; r < 4; r++) {
            const float mnew = fmaxf(m_st[r], rmax[r]);
            alpha[r] = __expf(m_st[r] - mnew);
            m_st[r] = mnew;
            rsum[r] = 0.0f;
        }
#pragma unroll
        for (int n = 0; n < 8; n++)
#pragma unroll
            for (int r = 0; r < 4; r++) {
                const float p = __expf(s[n][r] - m_st[r]);
                s[n][r] = p;
                rsum[r] += p;
            }
#pragma unroll
        for (int d = 1; d < 16; d <<= 1)
#pragma unroll
            for (int r = 0; r < 4; r++)
                rsum[r] += __shfl_xor(rsum[r], d, 64);
#pragma unroll
        for (int r = 0; r < 4; r++)
            l_st[r] = l_st[r] * alpha[r] + rsum[r];
#pragma unroll
        for (int dj = 0; dj < 4; dj++)
#pragma unroll
            for (int r = 0; r < 4; r++) o[dj][r] *= alpha[r];

        // P -> LDS
#pragma unroll
        for (int n = 0; n < 8; n++)
#pragma unroll
            for (int r = 0; r < 4; r++)
                Ps[(wave * 16 + quad * 4 + r) * 136 + n * 16 + l15] = f2b(s[n][r]);

        __syncthreads();   // (c) order P store -> P reload

        // O += P @ V : 4 k-steps over 128 kv positions
#pragma unroll
        for (int ks = 0; ks < 4; ks++) {
            const bf16x8 ap = *(const bf16x8*)&Ps[(wave * 16 + l15) * 136 + ks * 32 + kc];
#pragma unroll
            for (int dj = 0; dj < 4; dj++) {
                const bf16x8 bv = *(const bf16x8*)&Vts[(dj * 16 + l15) * 136 + ks * 32 + kc];
                o[dj] = __builtin_amdgcn_mfma_f32_16x16x32_bf16(ap, bv, o[dj], 0, 0, 0);
            }
        }
    }

    // epilogue: normalize, write bf16 [B,S,E]
    const int b = bh >> 4, h = bh & 15;
#pragma unroll
    for (int dj = 0; dj < 4; dj++)
#pragma unroll
        for (int r = 0; r < 4; r++) {
            const int sq = qt * 64 + wave * 16 + quad * 4 + r;
            const int col = h * 64 + dj * 16 + l15;
            AO[(b * 2048 + sq) * 1024 + col] = f2b(o[dj][r] / l_st[r]);
        }
}

extern "C" void kernel_launch(void* const* d_in, const int* in_sizes, int n_in,
                              void* d_out, int out_size, void* d_ws, size_t ws_size,
                              hipStream_t stream)
{
    (void)in_sizes; (void)n_in; (void)out_size; (void)ws_size;
    const float* value = (const float*)d_in[0];
    const float* key_  = (const float*)d_in[1];
    const float* query = (const float*)d_in[2];
    const float* Wv = (const float*)d_in[3];
    const float* bv = (const float*)d_in[4];
    const float* Wk = (const float*)d_in[5];
    const float* bk = (const float*)d_in[6];
    const float* Wq = (const float*)d_in[7];
    const float* bq = (const float*)d_in[8];
    const float* Wo = (const float*)d_in[9];
    const float* bo = (const float*)d_in[10];

    u16* ws = (u16*)d_ws;
    u16* WT = ws;                          // 4 x 1M bf16 (order: v,k,q,o)
    u16* Q  = ws + 4 * 1024 * 1024;        // 8M bf16 [B,H,S,D]
    u16* K  = Q + 8 * 1024 * 1024;         // 8M
    u16* V  = K + 8 * 1024 * 1024;         // 8M; dead after transpose_v -> reused as AO
    u16* VTr= V + 8 * 1024 * 1024;         // 8M [B,H,D,S]
    u16* AO = V;                           // alias: V consumed before attn writes AO

    transpose_w<<<dim3(16, 16, 4), dim3(256), 0, stream>>>(Wv, Wk, Wq, Wo, WT);
    qkv_kernel<<<dim3(8, 64, 3), dim3(256), 0, stream>>>(query, key_, value, WT,
                                                         bq, bk, bv, Q, K, V);
    transpose_v<<<dim3(32, 64), dim3(256), 0, stream>>>(V, VTr);
    attn_kernel<<<dim3(32, 64), dim3(256), 0, stream>>>(Q, K, VTr, AO);
    oproj_kernel<<<dim3(8, 64, 1), dim3(256), 0, stream>>>(AO, WT, bo, (float*)d_out);
}